// Round 6
// baseline (70.075 us; speedup 1.0000x reference)
//
#include <hip/hip_runtime.h>
#include <stdint.h>

#define N_DET    4096
#define MAX_DET  100
#define NTHREADS 1024
#define DEC_THREADS 512
#define DEC_CHUNKS  8        // blocks per batch in decode kernel
#define IOU_THR  0.5f

typedef unsigned long long u64;

// Explicit-rounding helpers: prevent -ffp-contract=fast from FMA-fusing and
// changing bits vs the JAX/NumPy reference (R1-R5 all passed with absmax 0.0).
__device__ __forceinline__ float fadd(float a, float b) { return __fadd_rn(a, b); }
__device__ __forceinline__ float fsub(float a, float b) { return __fsub_rn(a, b); }
__device__ __forceinline__ float fmul(float a, float b) { return __fmul_rn(a, b); }

struct Box { float x1, y1, x2, y2; };

__device__ __forceinline__ Box decode_box(const float* __restrict__ box_b,
                                          const int*   __restrict__ idx_b,
                                          const float* __restrict__ anchors,
                                          int i, float sz0, float sz1)
{
    int ai = idx_b[i];
    float a0 = anchors[ai * 4 + 0];
    float a1 = anchors[ai * 4 + 1];
    float a2 = anchors[ai * 4 + 2];
    float a3 = anchors[ai * 4 + 3];
    float yc_a = fmul(fadd(a0, a2), 0.5f);
    float xc_a = fmul(fadd(a1, a3), 0.5f);
    float ha = fsub(a2, a0);
    float wa = fsub(a3, a1);
    float ty = box_b[i * 4 + 0];
    float tx = box_b[i * 4 + 1];
    float th = box_b[i * 4 + 2];
    float tw = box_b[i * 4 + 3];
    float we = fmul(expf(tw), wa);
    float he = fmul(expf(th), ha);
    float yc = fadd(fmul(ty, ha), yc_a);
    float xc = fadd(fmul(tx, wa), xc_a);
    Box r;
    r.x1 = fsub(xc, fmul(we, 0.5f));
    r.y1 = fsub(yc, fmul(he, 0.5f));
    r.x2 = fadd(xc, fmul(we, 0.5f));
    r.y2 = fadd(yc, fmul(he, 0.5f));
    r.x1 = fminf(fmaxf(r.x1, 0.f), sz0);
    r.y1 = fminf(fmaxf(r.y1, 0.f), sz1);
    r.x2 = fminf(fmaxf(r.x2, 0.f), sz0);
    r.y2 = fminf(fmaxf(r.y2, 0.f), sz1);
    return r;
}

__device__ __forceinline__ float sigmoidf_ref(float x)
{
    return __fdiv_rn(1.0f, __fadd_rn(1.0f, expf(-x)));
}

// head (earlier-selected) first: union = area[head] + area[cand] - inter
__device__ __forceinline__ bool iou_suppress(float hx1, float hy1, float hx2, float hy2, float har,
                                             float cx1, float cy1, float cx2, float cy2, float car)
{
    float lt0 = fmaxf(hx1, cx1);
    float lt1 = fmaxf(hy1, cy1);
    float rb0 = fminf(hx2, cx2);
    float rb1 = fminf(hy2, cy2);
    float w0 = fmaxf(fsub(rb0, lt0), 0.f);
    float w1 = fmaxf(fsub(rb1, lt1), 0.f);
    float inter = fmul(w0, w1);
    float uni = fsub(fadd(har, car), inter);
    float iou = __fdiv_rn(inter, fmaxf(uni, 1e-8f));
    return iou > IOU_THR;
}

// ---- bitonic helpers (register / shuffle) ----
__device__ __forceinline__ u64 shfl_xor_u64(u64 x, int mask)
{
    unsigned lo = (unsigned)x, hi = (unsigned)(x >> 32);
    lo = __shfl_xor(lo, mask, 64);
    hi = __shfl_xor(hi, mask, 64);
    return ((u64)hi << 32) | lo;
}

__device__ __forceinline__ void cex(u64& a, u64& b, bool desc)
{
    bool sw = desc ? (a < b) : (a > b);
    u64 ta = a, tb = b;
    a = sw ? tb : ta;
    b = sw ? ta : tb;
}

__device__ __forceinline__ void shuf_pass(u64 e[4], int d, bool desc, int l)
{
    bool lower = ((l & d) == 0);
    bool keepmax = (desc == lower);
    #pragma unroll
    for (int s = 0; s < 4; ++s) {
        u64 p = shfl_xor_u64(e[s], d);
        u64 mx = (e[s] > p) ? e[s] : p;
        u64 mn = (e[s] < p) ? e[s] : p;
        e[s] = keepmax ? mx : mn;
    }
}

// =====================  Kernel 1: wide-grid decode  =====================
// grid = B * DEC_CHUNKS blocks x 512 threads; thread -> one box.
__global__ __launch_bounds__(DEC_THREADS)
void decode_kernel(const float* __restrict__ cls_outputs,
                   const float* __restrict__ box_outputs,
                   const int*   __restrict__ indices,
                   const float* __restrict__ anchors,
                   const float* __restrict__ img_scale,
                   const float* __restrict__ img_size,
                   float*       __restrict__ wmax,    // B * DEC_CHUNKS
                   u64*         __restrict__ wkeys,   // B * N_DET
                   float4*      __restrict__ wboxes)  // B * N_DET
{
    const int blk   = blockIdx.x;
    const int b     = blk / DEC_CHUNKS;
    const int chunk = blk % DEC_CHUNKS;
    const int i     = chunk * DEC_THREADS + threadIdx.x;

    const float* cls_b = cls_outputs + (size_t)b * N_DET;
    const float* box_b = box_outputs + (size_t)b * N_DET * 4;
    const int*   idx_b = indices + (size_t)b * N_DET;
    const float  scale = img_scale[b];
    const float  sz0   = __fdiv_rn(img_size[b * 2 + 0], scale);
    const float  sz1   = __fdiv_rn(img_size[b * 2 + 1], scale);

    Box r = decode_box(box_b, idx_b, anchors, i, sz0, sz1);
    float sc = sigmoidf_ref(cls_b[i]);

    wboxes[(size_t)b * N_DET + i] = make_float4(r.x1, r.y1, r.x2, r.y2);
    wkeys[(size_t)b * N_DET + i] =
        ((u64)__float_as_uint(sc) << 32) | (unsigned)(N_DET - 1 - i);

    // block max of clamped coords (max is order-independent; no NaNs possible)
    float lmax = fmaxf(fmaxf(r.x1, r.y1), fmaxf(r.x2, r.y2));
    for (int o = 32; o; o >>= 1) lmax = fmaxf(lmax, __shfl_xor(lmax, o, 64));
    __shared__ float wred[8];
    if ((threadIdx.x & 63) == 0) wred[threadIdx.x >> 6] = lmax;
    __syncthreads();
    if (threadIdx.x == 0) {
        float m = wred[0];
        #pragma unroll
        for (int k = 1; k < 8; ++k) m = fmaxf(m, wred[k]);
        wmax[b * DEC_CHUNKS + chunk] = m;   // plain store: overwritten every replay
    }
}

// =====================  Kernel 2: sort + scan + emit  =====================
__global__ __launch_bounds__(NTHREADS, 1)
void sort_scan_kernel(const int*   __restrict__ classes,    // B,N
                      const float* __restrict__ img_scale,  // B
                      const float* __restrict__ wmax,
                      const u64*   __restrict__ wkeys,
                      const float4* __restrict__ wboxes,
                      float*       __restrict__ out)        // B,MAX_DET,6
{
    __shared__ u64    keys[N_DET];     // 32 KB, globally sorted descending after phase B
    __shared__ float4 sbx[N_DET];      // 64 KB: shifted x1,y1,x2,y2 (by orig index)
    __shared__ float  sar[N_DET];      // 16 KB: shifted-box area
    __shared__ int    sel[MAX_DET];
    __shared__ float  selsc[MAX_DET];
    __shared__ float  hdx1[MAX_DET], hdy1[MAX_DET], hdx2[MAX_DET], hdy2[MAX_DET], hdar[MAX_DET];

    const int b = blockIdx.x;
    const int t = threadIdx.x;
    const int l = t & 63;              // lane

    const int*  cls_id_b = classes + (size_t)b * N_DET;
    const float scale    = img_scale[b];
    const u64*    wk = wkeys  + (size_t)b * N_DET;
    const float4* wb = wboxes + (size_t)b * N_DET;

    // M = max over batch (8 chunk maxima) + 1.0
    float mm = wmax[b * DEC_CHUNKS + 0];
    #pragma unroll
    for (int k = 1; k < DEC_CHUNKS; ++k) mm = fmaxf(mm, wmax[b * DEC_CHUNKS + k]);
    const float M = fadd(mm, 1.0f);    // jnp.max(b) + 1.0

    // ---------- load keys (blocked: thread t owns 4t..4t+3); fill sbx/sar ----------
    u64 e[4];
    const int4 cid4 = ((const int4*)cls_id_b)[t];
    const int  cids[4] = { cid4.x, cid4.y, cid4.z, cid4.w };
    #pragma unroll
    for (int s = 0; s < 4; ++s) {
        int i = 4 * t + s;
        e[s] = wk[i];
        float4 r = wb[i];
        float off = fmul((float)cids[s], M);   // c.astype(f32) * (max+1)
        float x1 = fadd(r.x, off), y1 = fadd(r.y, off);
        float x2 = fadd(r.z, off), y2 = fadd(r.w, off);
        sbx[i] = make_float4(x1, y1, x2, y2);
        sar[i] = fmul(fmaxf(fsub(x2, x1), 0.f), fmaxf(fsub(y2, y1), 0.f));
    }

    // ---------- Phase A (validated): wave-local bitonic, k=2..256 ----------
    cex(e[0], e[1], true);
    cex(e[2], e[3], false);
    for (int k = 4; k <= 128; k <<= 1) {
        bool desc = (l & (k >> 2)) == 0;
        for (int j = k >> 1; j >= 4; j >>= 1) shuf_pass(e, j >> 2, desc, l);
        cex(e[0], e[2], desc); cex(e[1], e[3], desc);
        cex(e[0], e[1], desc); cex(e[2], e[3], desc);
    }
    {   // k = 256
        bool desc = ((t >> 6) & 1) == 0;
        for (int j = 128; j >= 4; j >>= 1) shuf_pass(e, j >> 2, desc, l);
        cex(e[0], e[2], desc); cex(e[1], e[3], desc);
        cex(e[0], e[1], desc); cex(e[2], e[3], desc);
    }
    #pragma unroll
    for (int s = 0; s < 4; ++s) keys[4 * t + s] = e[s];

    // ---------- Phase B (validated): cross-wave merges k = 512..4096 ----------
    for (int k = 512; k <= N_DET; k <<= 1) {
        for (int j = k >> 1; j >= 256; j >>= 1) {
            __syncthreads();
            #pragma unroll
            for (int vv = 0; vv < 2; ++vv) {
                int v = t + vv * NTHREADS;
                int i   = ((v & ~(j - 1)) << 1) | (v & (j - 1));
                int ixj = i | j;
                bool desc = ((i & k) == 0);
                u64 a = keys[i], c = keys[ixj];
                bool sw = desc ? (a < c) : (a > c);
                if (sw) { keys[i] = c; keys[ixj] = a; }
            }
        }
        __syncthreads();
        u64 f[4];
        #pragma unroll
        for (int s = 0; s < 4; ++s) f[s] = keys[4 * t + s];
        bool desc = (t & (k >> 2)) == 0;
        for (int j = 128; j >= 4; j >>= 1) shuf_pass(f, j >> 2, desc, l);
        cex(f[0], f[2], desc); cex(f[1], f[3], desc);
        cex(f[0], f[1], desc); cex(f[2], f[3], desc);
        #pragma unroll
        for (int s = 0; s < 4; ++s) keys[4 * t + s] = f[s];
    }
    __syncthreads();   // sorted keys + sbx/sar visible

    // ---------- Single-wave batch-parallel greedy scan (validated R5) ----------
    if (t >= 64) return;
    const int lane = t;

    for (int r = lane; r < MAX_DET; r += 64) sel[r] = -1;

    int count = 0;
    for (int c = 0; c < N_DET && count < MAX_DET; c += 64) {
        int  pos  = c + lane;
        bool oob  = (pos >= N_DET);
        u64  key  = keys[oob ? (N_DET - 1) : pos];
        int  orig = N_DET - 1 - (int)(unsigned)(key & 0xFFFFFFFFull);
        float4 c4 = sbx[orig];
        float car = sar[orig];

        bool sup = oob;
        for (int k = 0; k < count; ++k) {
            sup = sup || iou_suppress(hdx1[k], hdy1[k], hdx2[k], hdy2[k], hdar[k],
                                      c4.x, c4.y, c4.z, c4.w, car);
        }
        u64 ext = __ballot(sup ? 1 : 0);

        u64 C = 0;
        for (int r = 1; r < 64; ++r) {
            int q = (lane + r) & 63;
            float qx1 = __shfl(c4.x, q, 64);
            float qy1 = __shfl(c4.y, q, 64);
            float qx2 = __shfl(c4.z, q, 64);
            float qy2 = __shfl(c4.w, q, 64);
            float qar = __shfl(car,  q, 64);
            bool hit = (q > lane) && !oob && (c + q < N_DET) &&
                       iou_suppress(c4.x, c4.y, c4.z, c4.w, car,
                                    qx1, qy1, qx2, qy2, qar);
            C |= ((u64)(hit ? 1 : 0)) << q;
        }
        u64 hasC = __ballot(C != 0ull);

        u64 alive = ~ext;
        u64 selmask = 0;
        int total = count;
        while (alive && total < MAX_DET) {
            int k = __ffsll(alive) - 1;
            selmask |= (1ull << k);
            alive &= ~(1ull << k);
            ++total;
            if ((hasC >> k) & 1ull) {
                unsigned clo = __shfl((int)(unsigned)C, k, 64);
                unsigned chi = __shfl((int)(unsigned)(C >> 32), k, 64);
                alive &= ~(((u64)chi << 32) | clo);
            }
        }

        if ((selmask >> lane) & 1ull) {
            int p = count + __popcll(selmask & ((1ull << lane) - 1ull));
            hdx1[p] = c4.x; hdy1[p] = c4.y; hdx2[p] = c4.z; hdy2[p] = c4.w; hdar[p] = car;
            sel[p] = orig;
            selsc[p] = __uint_as_float((unsigned)(key >> 32));   // exact sigmoid bits
        }
        count = total;
    }

    // ---------- Emit (no anchor gathers: box from ws, score from key) ----------
    for (int r = lane; r < MAX_DET; r += 64) {
        int sidx = sel[r];
        float* o = out + (size_t)b * MAX_DET * 6 + (size_t)r * 6;
        if (sidx < 0) {
            o[0] = 0.f; o[1] = 0.f; o[2] = 0.f; o[3] = 0.f; o[4] = 0.f; o[5] = 0.f;
        } else {
            float4 bb = wb[sidx];
            int c = cls_id_b[sidx];
            o[0] = fmul(bb.x, scale);
            o[1] = fmul(bb.y, scale);
            o[2] = fmul(bb.z, scale);
            o[3] = fmul(bb.w, scale);
            o[4] = selsc[r];
            o[5] = (float)(c + 1);
        }
    }
}

extern "C" void kernel_launch(void* const* d_in, const int* in_sizes, int n_in,
                              void* d_out, int out_size, void* d_ws, size_t ws_size,
                              hipStream_t stream)
{
    const float* cls_outputs = (const float*)d_in[0];
    const float* box_outputs = (const float*)d_in[1];
    const int*   indices     = (const int*)d_in[2];
    const int*   classes     = (const int*)d_in[3];
    const float* anchors     = (const float*)d_in[4];
    const float* img_scale   = (const float*)d_in[5];
    const float* img_size    = (const float*)d_in[6];
    float*       out         = (float*)d_out;

    const int B = in_sizes[5];   // img_scale has B elements

    // workspace layout: [wmax: B*8 floats][pad to 1KB][wkeys: B*4096 u64][wboxes: B*4096 float4]
    char* wsb = (char*)d_ws;
    float*  wmax   = (float*)wsb;
    u64*    wkeys  = (u64*)(wsb + 1024);
    float4* wboxes = (float4*)(wsb + 1024 + (size_t)B * N_DET * sizeof(u64));

    decode_kernel<<<dim3(B * DEC_CHUNKS), dim3(DEC_THREADS), 0, stream>>>(
        cls_outputs, box_outputs, indices, anchors, img_scale, img_size,
        wmax, wkeys, wboxes);

    sort_scan_kernel<<<dim3(B), dim3(NTHREADS), 0, stream>>>(
        classes, img_scale, wmax, wkeys, wboxes, out);
}

// Round 7
// 47.992 us; speedup vs baseline: 1.4602x; 1.4602x over previous
//
#include <hip/hip_runtime.h>
#include <stdint.h>

#define N_DET    4096
#define MAX_DET  100
#define NTHREADS 1024
#define DEC_THREADS 512
#define DEC_CHUNKS  8        // blocks per batch in decode kernel
#define IOU_THR  0.5f

typedef unsigned long long u64;

// Explicit-rounding helpers: prevent -ffp-contract=fast from FMA-fusing and
// changing bits vs the JAX/NumPy reference (R1-R6 all passed with absmax 0.0).
__device__ __forceinline__ float fadd(float a, float b) { return __fadd_rn(a, b); }
__device__ __forceinline__ float fsub(float a, float b) { return __fsub_rn(a, b); }
__device__ __forceinline__ float fmul(float a, float b) { return __fmul_rn(a, b); }

struct Box { float x1, y1, x2, y2; };

__device__ __forceinline__ Box decode_box(const float* __restrict__ box_b,
                                          const int*   __restrict__ idx_b,
                                          const float* __restrict__ anchors,
                                          int i, float sz0, float sz1)
{
    int ai = idx_b[i];
    float a0 = anchors[ai * 4 + 0];
    float a1 = anchors[ai * 4 + 1];
    float a2 = anchors[ai * 4 + 2];
    float a3 = anchors[ai * 4 + 3];
    float yc_a = fmul(fadd(a0, a2), 0.5f);
    float xc_a = fmul(fadd(a1, a3), 0.5f);
    float ha = fsub(a2, a0);
    float wa = fsub(a3, a1);
    float ty = box_b[i * 4 + 0];
    float tx = box_b[i * 4 + 1];
    float th = box_b[i * 4 + 2];
    float tw = box_b[i * 4 + 3];
    float we = fmul(expf(tw), wa);
    float he = fmul(expf(th), ha);
    float yc = fadd(fmul(ty, ha), yc_a);
    float xc = fadd(fmul(tx, wa), xc_a);
    Box r;
    r.x1 = fsub(xc, fmul(we, 0.5f));
    r.y1 = fsub(yc, fmul(he, 0.5f));
    r.x2 = fadd(xc, fmul(we, 0.5f));
    r.y2 = fadd(yc, fmul(he, 0.5f));
    r.x1 = fminf(fmaxf(r.x1, 0.f), sz0);
    r.y1 = fminf(fmaxf(r.y1, 0.f), sz1);
    r.x2 = fminf(fmaxf(r.x2, 0.f), sz0);
    r.y2 = fminf(fmaxf(r.y2, 0.f), sz1);
    return r;
}

__device__ __forceinline__ float sigmoidf_ref(float x)
{
    return __fdiv_rn(1.0f, __fadd_rn(1.0f, expf(-x)));
}

// head (earlier-selected) first: union = area[head] + area[cand] - inter
__device__ __forceinline__ bool iou_suppress(float hx1, float hy1, float hx2, float hy2, float har,
                                             float cx1, float cy1, float cx2, float cy2, float car)
{
    float lt0 = fmaxf(hx1, cx1);
    float lt1 = fmaxf(hy1, cy1);
    float rb0 = fminf(hx2, cx2);
    float rb1 = fminf(hy2, cy2);
    float w0 = fmaxf(fsub(rb0, lt0), 0.f);
    float w1 = fmaxf(fsub(rb1, lt1), 0.f);
    float inter = fmul(w0, w1);
    float uni = fsub(fadd(har, car), inter);
    float iou = __fdiv_rn(inter, fmaxf(uni, 1e-8f));
    return iou > IOU_THR;
}

// ---- bitonic helpers (register / shuffle) ----
__device__ __forceinline__ u64 shfl_xor_u64(u64 x, int mask)
{
    unsigned lo = (unsigned)x, hi = (unsigned)(x >> 32);
    lo = __shfl_xor(lo, mask, 64);
    hi = __shfl_xor(hi, mask, 64);
    return ((u64)hi << 32) | lo;
}

__device__ __forceinline__ void cex(u64& a, u64& b, bool desc)
{
    bool sw = desc ? (a < b) : (a > b);
    u64 ta = a, tb = b;
    a = sw ? tb : ta;
    b = sw ? ta : tb;
}

__device__ __forceinline__ void shuf_pass(u64 e[4], int d, bool desc, int l)
{
    bool lower = ((l & d) == 0);
    bool keepmax = (desc == lower);
    #pragma unroll
    for (int s = 0; s < 4; ++s) {
        u64 p = shfl_xor_u64(e[s], d);
        u64 mx = (e[s] > p) ? e[s] : p;
        u64 mn = (e[s] < p) ? e[s] : p;
        e[s] = keepmax ? mx : mn;
    }
}

// =====================  Kernel 1: wide-grid decode (validated R6)  =====================
__global__ __launch_bounds__(DEC_THREADS)
void decode_kernel(const float* __restrict__ cls_outputs,
                   const float* __restrict__ box_outputs,
                   const int*   __restrict__ indices,
                   const float* __restrict__ anchors,
                   const float* __restrict__ img_scale,
                   const float* __restrict__ img_size,
                   float*       __restrict__ wmax,    // B * DEC_CHUNKS
                   u64*         __restrict__ wkeys,   // B * N_DET
                   float4*      __restrict__ wboxes)  // B * N_DET
{
    const int blk   = blockIdx.x;
    const int b     = blk / DEC_CHUNKS;
    const int chunk = blk % DEC_CHUNKS;
    const int i     = chunk * DEC_THREADS + threadIdx.x;

    const float* cls_b = cls_outputs + (size_t)b * N_DET;
    const float* box_b = box_outputs + (size_t)b * N_DET * 4;
    const int*   idx_b = indices + (size_t)b * N_DET;
    const float  scale = img_scale[b];
    const float  sz0   = __fdiv_rn(img_size[b * 2 + 0], scale);
    const float  sz1   = __fdiv_rn(img_size[b * 2 + 1], scale);

    Box r = decode_box(box_b, idx_b, anchors, i, sz0, sz1);
    float sc = sigmoidf_ref(cls_b[i]);

    wboxes[(size_t)b * N_DET + i] = make_float4(r.x1, r.y1, r.x2, r.y2);
    wkeys[(size_t)b * N_DET + i] =
        ((u64)__float_as_uint(sc) << 32) | (unsigned)(N_DET - 1 - i);

    float lmax = fmaxf(fmaxf(r.x1, r.y1), fmaxf(r.x2, r.y2));
    for (int o = 32; o; o >>= 1) lmax = fmaxf(lmax, __shfl_xor(lmax, o, 64));
    __shared__ float wred[8];
    if ((threadIdx.x & 63) == 0) wred[threadIdx.x >> 6] = lmax;
    __syncthreads();
    if (threadIdx.x == 0) {
        float m = wred[0];
        #pragma unroll
        for (int k = 1; k < 8; ++k) m = fmaxf(m, wred[k]);
        wmax[b * DEC_CHUNKS + chunk] = m;   // plain store: overwritten every replay
    }
}

// =====================  Kernel 2: sort + block-parallel scan + emit  =====================
__global__ __launch_bounds__(NTHREADS, 1)
void sort_scan_kernel(const int*   __restrict__ classes,    // B,N
                      const float* __restrict__ img_scale,  // B
                      const float* __restrict__ wmax,
                      const u64*   __restrict__ wkeys,
                      const float4* __restrict__ wboxes,
                      float*       __restrict__ out)        // B,MAX_DET,6
{
    __shared__ u64    keys[N_DET];     // 32 KB, globally sorted descending after phase B
    __shared__ float4 sbx[N_DET];      // 64 KB: shifted x1,y1,x2,y2 (by orig index)
    __shared__ float  sar[N_DET];      // 16 KB: shifted-box area
    __shared__ int    sel[MAX_DET];
    __shared__ float  selsc[MAX_DET];
    __shared__ float4 hbox4[MAX_DET];  // selected heads (shifted box)
    __shared__ float  harr[MAX_DET];   // selected heads (area)
    // per-batch scan state
    __shared__ float4 bbox[64];
    __shared__ float  barr[64];
    __shared__ int    borig[64];
    __shared__ u64    bkey[64];
    __shared__ u64    extp[16];        // per-headgroup suppression ballots
    __shared__ unsigned Cplo[16][64];  // pair-matrix partials (lo 32 bits), [group][cand]
    __shared__ unsigned Cphi[16][64];
    __shared__ int    sh_count;

    const int b = blockIdx.x;
    const int t = threadIdx.x;
    const int l = t & 63;              // lane

    const int*  cls_id_b = classes + (size_t)b * N_DET;
    const float scale    = img_scale[b];
    const u64*    wk = wkeys  + (size_t)b * N_DET;
    const float4* wb = wboxes + (size_t)b * N_DET;

    // M = max over batch (8 chunk maxima) + 1.0
    float mm = wmax[b * DEC_CHUNKS + 0];
    #pragma unroll
    for (int k = 1; k < DEC_CHUNKS; ++k) mm = fmaxf(mm, wmax[b * DEC_CHUNKS + k]);
    const float M = fadd(mm, 1.0f);    // jnp.max(b) + 1.0

    // ---------- load keys (blocked); fill sbx/sar ----------
    u64 e[4];
    const int4 cid4 = ((const int4*)cls_id_b)[t];
    const int  cids[4] = { cid4.x, cid4.y, cid4.z, cid4.w };
    #pragma unroll
    for (int s = 0; s < 4; ++s) {
        int i = 4 * t + s;
        e[s] = wk[i];
        float4 r = wb[i];
        float off = fmul((float)cids[s], M);   // c.astype(f32) * (max+1)
        float x1 = fadd(r.x, off), y1 = fadd(r.y, off);
        float x2 = fadd(r.z, off), y2 = fadd(r.w, off);
        sbx[i] = make_float4(x1, y1, x2, y2);
        sar[i] = fmul(fmaxf(fsub(x2, x1), 0.f), fmaxf(fsub(y2, y1), 0.f));
    }

    // ---------- Phase A (validated): wave-local bitonic, k=2..256 ----------
    cex(e[0], e[1], true);
    cex(e[2], e[3], false);
    for (int k = 4; k <= 128; k <<= 1) {
        bool desc = (l & (k >> 2)) == 0;
        for (int j = k >> 1; j >= 4; j >>= 1) shuf_pass(e, j >> 2, desc, l);
        cex(e[0], e[2], desc); cex(e[1], e[3], desc);
        cex(e[0], e[1], desc); cex(e[2], e[3], desc);
    }
    {   // k = 256
        bool desc = ((t >> 6) & 1) == 0;
        for (int j = 128; j >= 4; j >>= 1) shuf_pass(e, j >> 2, desc, l);
        cex(e[0], e[2], desc); cex(e[1], e[3], desc);
        cex(e[0], e[1], desc); cex(e[2], e[3], desc);
    }
    #pragma unroll
    for (int s = 0; s < 4; ++s) keys[4 * t + s] = e[s];

    // ---------- Phase B (validated): cross-wave merges k = 512..4096 ----------
    for (int k = 512; k <= N_DET; k <<= 1) {
        for (int j = k >> 1; j >= 256; j >>= 1) {
            __syncthreads();
            #pragma unroll
            for (int vv = 0; vv < 2; ++vv) {
                int v = t + vv * NTHREADS;
                int i   = ((v & ~(j - 1)) << 1) | (v & (j - 1));
                int ixj = i | j;
                bool desc = ((i & k) == 0);
                u64 a = keys[i], c = keys[ixj];
                bool sw = desc ? (a < c) : (a > c);
                if (sw) { keys[i] = c; keys[ixj] = a; }
            }
        }
        __syncthreads();
        u64 f[4];
        #pragma unroll
        for (int s = 0; s < 4; ++s) f[s] = keys[4 * t + s];
        bool desc = (t & (k >> 2)) == 0;
        for (int j = 128; j >= 4; j >>= 1) shuf_pass(f, j >> 2, desc, l);
        cex(f[0], f[2], desc); cex(f[1], f[3], desc);
        cex(f[0], f[1], desc); cex(f[2], f[3], desc);
        #pragma unroll
        for (int s = 0; s < 4; ++s) keys[4 * t + s] = f[s];
    }
    // scan-state init folded into the final sort barrier
    if (t < MAX_DET) sel[t] = -1;
    if (t == 0) sh_count = 0;
    __syncthreads();   // sorted keys + sbx/sar + init visible

    // ---------- Block-parallel greedy scan (exact reference order) ----------
    const int j = t & 63;      // candidate slot
    const int g = t >> 6;      // work group (wave index)

    for (int c = 0; c < N_DET; c += 64) {
        int count = sh_count;              // uniform (read after barrier)
        if (count >= MAX_DET) break;

        // 1. wave 0 publishes the batch
        if (t < 64) {
            int pos = c + t;
            u64 key = keys[(pos < N_DET) ? pos : (N_DET - 1)];
            int orig = N_DET - 1 - (int)(unsigned)(key & 0xFFFFFFFFull);
            bkey[t] = key; borig[t] = orig;
            bbox[t] = sbx[orig]; barr[t] = sar[orig];
        }
        __syncthreads();

        float4 c4 = bbox[j];
        float  car = barr[j];
        const bool oob = (c + j >= N_DET);

        // 2a. ext-suppression partials: group g checks heads g, g+16, ...
        bool sup = oob;
        for (int k = g; k < count; k += 16) {
            float4 h4 = hbox4[k];
            sup = sup | iou_suppress(h4.x, h4.y, h4.z, h4.w, harr[k],
                                     c4.x, c4.y, c4.z, c4.w, car);
        }
        u64 bal = __ballot(sup ? 1 : 0);
        if ((t & 63) == 0) extp[g] = bal;

        // 2b. pair-matrix partials: XOR enumeration, group g handles r = g+1, g+17, ...
        unsigned cplo = 0, cphi = 0;
        for (int r = g + 1; r < 64; r += 16) {
            int q = j ^ r;
            float4 q4 = bbox[q];
            float qar = barr[q];
            bool hit = (q > j) & (!oob) & ((c + q) < N_DET) &
                       iou_suppress(c4.x, c4.y, c4.z, c4.w, car,
                                    q4.x, q4.y, q4.z, q4.w, qar);
            unsigned bit = hit ? 1u : 0u;
            if (q < 32) cplo |= bit << q; else cphi |= bit << (q - 32);
        }
        Cplo[g][j] = cplo;
        Cphi[g][j] = cphi;
        __syncthreads();

        // 3. wave 0: combine partials, exact greedy closure, append heads
        if (t < 64) {
            const int lane = t;
            u64 ext = 0;
            #pragma unroll
            for (int gg = 0; gg < 16; ++gg) ext |= extp[gg];
            unsigned lo = 0, hi = 0;
            #pragma unroll
            for (int gg = 0; gg < 16; ++gg) { lo |= Cplo[gg][lane]; hi |= Cphi[gg][lane]; }
            u64 C = ((u64)hi << 32) | lo;
            u64 hasC = __ballot(C != 0ull);

            u64 alive = ~ext;
            u64 selmask = 0;
            int total = count;
            while (alive && total < MAX_DET) {
                int k = __ffsll(alive) - 1;
                selmask |= (1ull << k);
                alive &= ~(1ull << k);
                ++total;
                if ((hasC >> k) & 1ull) {
                    unsigned clo = __shfl((int)(unsigned)C, k, 64);
                    unsigned chi = __shfl((int)(unsigned)(C >> 32), k, 64);
                    alive &= ~(((u64)chi << 32) | clo);
                }
            }

            if ((selmask >> lane) & 1ull) {
                int p = count + __popcll(selmask & ((1ull << lane) - 1ull));
                hbox4[p] = c4; harr[p] = car;
                sel[p] = borig[lane];
                selsc[p] = __uint_as_float((unsigned)(bkey[lane] >> 32));  // exact sigmoid bits
            }
            if (lane == 0) sh_count = total;
        }
        __syncthreads();
    }

    // ---------- Emit (wave 0; no anchor gathers) ----------
    if (t >= 64) return;
    for (int r = t; r < MAX_DET; r += 64) {
        int sidx = sel[r];
        float* o = out + (size_t)b * MAX_DET * 6 + (size_t)r * 6;
        if (sidx < 0) {
            o[0] = 0.f; o[1] = 0.f; o[2] = 0.f; o[3] = 0.f; o[4] = 0.f; o[5] = 0.f;
        } else {
            float4 bb = wb[sidx];
            int c = cls_id_b[sidx];
            o[0] = fmul(bb.x, scale);
            o[1] = fmul(bb.y, scale);
            o[2] = fmul(bb.z, scale);
            o[3] = fmul(bb.w, scale);
            o[4] = selsc[r];
            o[5] = (float)(c + 1);
        }
    }
}

extern "C" void kernel_launch(void* const* d_in, const int* in_sizes, int n_in,
                              void* d_out, int out_size, void* d_ws, size_t ws_size,
                              hipStream_t stream)
{
    const float* cls_outputs = (const float*)d_in[0];
    const float* box_outputs = (const float*)d_in[1];
    const int*   indices     = (const int*)d_in[2];
    const int*   classes     = (const int*)d_in[3];
    const float* anchors     = (const float*)d_in[4];
    const float* img_scale   = (const float*)d_in[5];
    const float* img_size    = (const float*)d_in[6];
    float*       out         = (float*)d_out;

    const int B = in_sizes[5];   // img_scale has B elements

    // workspace layout: [wmax: B*8 floats][pad to 1KB][wkeys: B*4096 u64][wboxes: B*4096 float4]
    char* wsb = (char*)d_ws;
    float*  wmax   = (float*)wsb;
    u64*    wkeys  = (u64*)(wsb + 1024);
    float4* wboxes = (float4*)(wsb + 1024 + (size_t)B * N_DET * sizeof(u64));

    decode_kernel<<<dim3(B * DEC_CHUNKS), dim3(DEC_THREADS), 0, stream>>>(
        cls_outputs, box_outputs, indices, anchors, img_scale, img_size,
        wmax, wkeys, wboxes);

    sort_scan_kernel<<<dim3(B), dim3(NTHREADS), 0, stream>>>(
        classes, img_scale, wmax, wkeys, wboxes, out);
}

// Round 8
// 41.414 us; speedup vs baseline: 1.6921x; 1.1588x over previous
//
#include <hip/hip_runtime.h>
#include <stdint.h>

#define N_DET    4096
#define HALF     2048
#define MAX_DET  100
#define NTHREADS 1024
#define SORT_THREADS 512
#define DEC_THREADS 512
#define DEC_CHUNKS  8        // blocks per batch in decode kernel
#define IOU_THR  0.5f

typedef unsigned long long u64;

// Explicit-rounding helpers: prevent -ffp-contract=fast from FMA-fusing and
// changing bits vs the JAX/NumPy reference (R1-R7 all passed with absmax 0.0).
__device__ __forceinline__ float fadd(float a, float b) { return __fadd_rn(a, b); }
__device__ __forceinline__ float fsub(float a, float b) { return __fsub_rn(a, b); }
__device__ __forceinline__ float fmul(float a, float b) { return __fmul_rn(a, b); }

struct Box { float x1, y1, x2, y2; };

__device__ __forceinline__ Box decode_box(const float* __restrict__ box_b,
                                          const int*   __restrict__ idx_b,
                                          const float* __restrict__ anchors,
                                          int i, float sz0, float sz1)
{
    int ai = idx_b[i];
    float a0 = anchors[ai * 4 + 0];
    float a1 = anchors[ai * 4 + 1];
    float a2 = anchors[ai * 4 + 2];
    float a3 = anchors[ai * 4 + 3];
    float yc_a = fmul(fadd(a0, a2), 0.5f);
    float xc_a = fmul(fadd(a1, a3), 0.5f);
    float ha = fsub(a2, a0);
    float wa = fsub(a3, a1);
    float ty = box_b[i * 4 + 0];
    float tx = box_b[i * 4 + 1];
    float th = box_b[i * 4 + 2];
    float tw = box_b[i * 4 + 3];
    float we = fmul(expf(tw), wa);
    float he = fmul(expf(th), ha);
    float yc = fadd(fmul(ty, ha), yc_a);
    float xc = fadd(fmul(tx, wa), xc_a);
    Box r;
    r.x1 = fsub(xc, fmul(we, 0.5f));
    r.y1 = fsub(yc, fmul(he, 0.5f));
    r.x2 = fadd(xc, fmul(we, 0.5f));
    r.y2 = fadd(yc, fmul(he, 0.5f));
    r.x1 = fminf(fmaxf(r.x1, 0.f), sz0);
    r.y1 = fminf(fmaxf(r.y1, 0.f), sz1);
    r.x2 = fminf(fmaxf(r.x2, 0.f), sz0);
    r.y2 = fminf(fmaxf(r.y2, 0.f), sz1);
    return r;
}

__device__ __forceinline__ float sigmoidf_ref(float x)
{
    return __fdiv_rn(1.0f, __fadd_rn(1.0f, expf(-x)));
}

// head (earlier-selected) first: union = area[head] + area[cand] - inter
__device__ __forceinline__ bool iou_suppress(float hx1, float hy1, float hx2, float hy2, float har,
                                             float cx1, float cy1, float cx2, float cy2, float car)
{
    float lt0 = fmaxf(hx1, cx1);
    float lt1 = fmaxf(hy1, cy1);
    float rb0 = fminf(hx2, cx2);
    float rb1 = fminf(hy2, cy2);
    float w0 = fmaxf(fsub(rb0, lt0), 0.f);
    float w1 = fmaxf(fsub(rb1, lt1), 0.f);
    float inter = fmul(w0, w1);
    float uni = fsub(fadd(har, car), inter);
    float iou = __fdiv_rn(inter, fmaxf(uni, 1e-8f));
    return iou > IOU_THR;
}

// ---- bitonic helpers (register / shuffle) ----
__device__ __forceinline__ u64 shfl_xor_u64(u64 x, int mask)
{
    unsigned lo = (unsigned)x, hi = (unsigned)(x >> 32);
    lo = __shfl_xor(lo, mask, 64);
    hi = __shfl_xor(hi, mask, 64);
    return ((u64)hi << 32) | lo;
}

__device__ __forceinline__ void cex(u64& a, u64& b, bool desc)
{
    bool sw = desc ? (a < b) : (a > b);
    u64 ta = a, tb = b;
    a = sw ? tb : ta;
    b = sw ? ta : tb;
}

__device__ __forceinline__ void shuf_pass(u64 e[4], int d, bool desc, int l)
{
    bool lower = ((l & d) == 0);
    bool keepmax = (desc == lower);
    #pragma unroll
    for (int s = 0; s < 4; ++s) {
        u64 p = shfl_xor_u64(e[s], d);
        u64 mx = (e[s] > p) ? e[s] : p;
        u64 mn = (e[s] < p) ? e[s] : p;
        e[s] = keepmax ? mx : mn;
    }
}

// 2-slot descending merge step: element idx = 2*lane + slot, partner lane = l ^ d.
__device__ __forceinline__ void shuf_pass2(u64 e[2], int d, int l)
{
    bool keepmax = ((l & d) == 0);
    #pragma unroll
    for (int s = 0; s < 2; ++s) {
        u64 p = shfl_xor_u64(e[s], d);
        u64 mx = (e[s] > p) ? e[s] : p;
        u64 mn = (e[s] < p) ? e[s] : p;
        e[s] = keepmax ? mx : mn;
    }
}

// =====================  Kernel 1: wide-grid decode (validated R6/R7)  =====================
__global__ __launch_bounds__(DEC_THREADS)
void decode_kernel(const float* __restrict__ cls_outputs,
                   const float* __restrict__ box_outputs,
                   const int*   __restrict__ indices,
                   const float* __restrict__ anchors,
                   const float* __restrict__ img_scale,
                   const float* __restrict__ img_size,
                   float*       __restrict__ wmax,    // B * DEC_CHUNKS
                   u64*         __restrict__ wkeys,   // B * N_DET
                   float4*      __restrict__ wboxes)  // B * N_DET
{
    const int blk   = blockIdx.x;
    const int b     = blk / DEC_CHUNKS;
    const int chunk = blk % DEC_CHUNKS;
    const int i     = chunk * DEC_THREADS + threadIdx.x;

    const float* cls_b = cls_outputs + (size_t)b * N_DET;
    const float* box_b = box_outputs + (size_t)b * N_DET * 4;
    const int*   idx_b = indices + (size_t)b * N_DET;
    const float  scale = img_scale[b];
    const float  sz0   = __fdiv_rn(img_size[b * 2 + 0], scale);
    const float  sz1   = __fdiv_rn(img_size[b * 2 + 1], scale);

    Box r = decode_box(box_b, idx_b, anchors, i, sz0, sz1);
    float sc = sigmoidf_ref(cls_b[i]);

    wboxes[(size_t)b * N_DET + i] = make_float4(r.x1, r.y1, r.x2, r.y2);
    wkeys[(size_t)b * N_DET + i] =
        ((u64)__float_as_uint(sc) << 32) | (unsigned)(N_DET - 1 - i);

    float lmax = fmaxf(fmaxf(r.x1, r.y1), fmaxf(r.x2, r.y2));
    for (int o = 32; o; o >>= 1) lmax = fmaxf(lmax, __shfl_xor(lmax, o, 64));
    __shared__ float wred[8];
    if ((threadIdx.x & 63) == 0) wred[threadIdx.x >> 6] = lmax;
    __syncthreads();
    if (threadIdx.x == 0) {
        float m = wred[0];
        #pragma unroll
        for (int k = 1; k < 8; ++k) m = fmaxf(m, wred[k]);
        wmax[b * DEC_CHUNKS + chunk] = m;   // plain store: overwritten every replay
    }
}

// =====================  Kernel 2: sort one 2048-half in place  =====================
// grid = B*2 blocks x 512 threads; block sorts wkeys[blk*2048 .. +2048) descending.
// Idempotent (bitonic on sorted input yields same output) -> replay-safe.
__global__ __launch_bounds__(SORT_THREADS, 1)
void sort_half_kernel(u64* __restrict__ wkeys)
{
    __shared__ u64 keys[HALF];     // 16 KB
    u64* gk = wkeys + (size_t)blockIdx.x * HALF;
    const int t = threadIdx.x;
    const int l = t & 63;

    u64 e[4];
    #pragma unroll
    for (int s = 0; s < 4; ++s) e[s] = gk[4 * t + s];

    // Phase A (validated): wave-local bitonic, k=2..256; i = 4t+s, desc <=> (i&k)==0
    cex(e[0], e[1], true);
    cex(e[2], e[3], false);
    for (int k = 4; k <= 128; k <<= 1) {
        bool desc = (l & (k >> 2)) == 0;
        for (int j = k >> 1; j >= 4; j >>= 1) shuf_pass(e, j >> 2, desc, l);
        cex(e[0], e[2], desc); cex(e[1], e[3], desc);
        cex(e[0], e[1], desc); cex(e[2], e[3], desc);
    }
    {   // k = 256: wave-parity direction
        bool desc = ((t >> 6) & 1) == 0;
        for (int j = 128; j >= 4; j >>= 1) shuf_pass(e, j >> 2, desc, l);
        cex(e[0], e[2], desc); cex(e[1], e[3], desc);
        cex(e[0], e[1], desc); cex(e[2], e[3], desc);
    }
    #pragma unroll
    for (int s = 0; s < 4; ++s) keys[4 * t + s] = e[s];

    // Phase B (validated formulas): cross-wave merges k = 512..2048
    for (int k = 512; k <= HALF; k <<= 1) {
        for (int j = k >> 1; j >= 256; j >>= 1) {
            __syncthreads();
            #pragma unroll
            for (int vv = 0; vv < 2; ++vv) {
                int v = t + vv * SORT_THREADS;          // 0..1023 pairs
                int i   = ((v & ~(j - 1)) << 1) | (v & (j - 1));
                int ixj = i | j;
                bool desc = ((i & k) == 0);
                u64 a = keys[i], c = keys[ixj];
                bool sw = desc ? (a < c) : (a > c);
                if (sw) { keys[i] = c; keys[ixj] = a; }
            }
        }
        __syncthreads();
        u64 f[4];
        #pragma unroll
        for (int s = 0; s < 4; ++s) f[s] = keys[4 * t + s];
        bool desc = (t & (k >> 2)) == 0;               // (4t&k)==0
        for (int j = 128; j >= 4; j >>= 1) shuf_pass(f, j >> 2, desc, l);
        cex(f[0], f[2], desc); cex(f[1], f[3], desc);
        cex(f[0], f[1], desc); cex(f[2], f[3], desc);
        #pragma unroll
        for (int s = 0; s < 4; ++s) keys[4 * t + s] = f[s];
    }
    __syncthreads();
    #pragma unroll
    for (int s = 0; s < 4; ++s) gk[4 * t + s] = keys[4 * t + s];
}

// =====================  Kernel 3: on-the-fly 2-way merge + block-parallel scan  =====================
__global__ __launch_bounds__(NTHREADS, 1)
void scan_kernel(const int*    __restrict__ classes,    // B,N
                 const float*  __restrict__ img_scale,  // B
                 const float*  __restrict__ wmax,
                 const u64*    __restrict__ wkeys,      // sorted halves
                 const float4* __restrict__ wboxes,
                 float*        __restrict__ out)        // B,MAX_DET,6
{
    __shared__ float4 bbox[64];
    __shared__ float  barr[64];
    __shared__ int    borig[64];
    __shared__ u64    bkey[64];
    __shared__ u64    extp[16];
    __shared__ unsigned Cplo[16][64];
    __shared__ unsigned Cphi[16][64];
    __shared__ int    sel[MAX_DET];
    __shared__ float  selsc[MAX_DET];
    __shared__ float4 hbox4[MAX_DET];
    __shared__ float  harr[MAX_DET];
    __shared__ int    sh_count;

    const int b = blockIdx.x;
    const int t = threadIdx.x;
    const int l = t & 63;

    const int*    cls_id_b = classes + (size_t)b * N_DET;
    const float   scale    = img_scale[b];
    const u64*    gA = wkeys + (size_t)b * N_DET;    // half A: orig 0..2047, desc
    const u64*    gB = gA + HALF;                    // half B: orig 2048..4095, desc
    const float4* wb = wboxes + (size_t)b * N_DET;

    float mm = wmax[b * DEC_CHUNKS + 0];
    #pragma unroll
    for (int k = 1; k < DEC_CHUNKS; ++k) mm = fmaxf(mm, wmax[b * DEC_CHUNKS + k]);
    const float M = fadd(mm, 1.0f);   // jnp.max(b) + 1.0

    if (t < MAX_DET) sel[t] = -1;
    if (t == 0) sh_count = 0;
    __syncthreads();

    int pa = 0, pb = 0;               // meaningful in wave 0 only (uniform there)
    const int j = t & 63;
    const int g = t >> 6;

    for (int c = 0; c < N_DET; c += 64) {
        int count = sh_count;          // uniform after barrier
        if (count >= MAX_DET) break;

        // ---- 1. wave 0: exact next-64 via bitonic merge of window A ++ reversed window B ----
        if (t < 64) {
            u64 ee[2];
            if (l < 32) {              // elements 2l, 2l+1  <- A[pa + 2l + s]
                int p0 = pa + 2 * l;
                ee[0] = (p0     < HALF) ? gA[p0]     : 0ull;
                ee[1] = (p0 + 1 < HALF) ? gA[p0 + 1] : 0ull;
            } else {                   // elements 64+p, p=2(l-32)+s <- B[pb + 63 - p]
                int p  = 2 * (l - 32);
                int q0 = pb + 63 - p;
                ee[0] = (q0     < HALF) ? gB[q0]     : 0ull;
                ee[1] = (q0 - 1 < HALF && q0 - 1 >= 0) ? gB[q0 - 1] : 0ull;
            }
            // A-desc | B-asc (with 0-sentinel padding) is bitonic; 7-step descending merge
            shuf_pass2(ee, 32, l); shuf_pass2(ee, 16, l); shuf_pass2(ee, 8, l);
            shuf_pass2(ee, 4, l);  shuf_pass2(ee, 2, l);  shuf_pass2(ee, 1, l);
            cex(ee[0], ee[1], true);

            // winners = elements 0..63 -> lanes 0..31 hold ranks 2l, 2l+1
            int orig0 = N_DET - 1 - (int)(unsigned)(ee[0] & 0xFFFFFFFFull);
            int orig1 = N_DET - 1 - (int)(unsigned)(ee[1] & 0xFFFFFFFFull);
            bool r0 = (l < 32) && (ee[0] != 0ull);
            bool r1 = (l < 32) && (ee[1] != 0ull);
            if (l < 32) {
                #pragma unroll
                for (int s = 0; s < 2; ++s) {
                    int  r    = 2 * l + s;
                    u64  key  = s ? ee[1] : ee[0];
                    int  orig = s ? orig1 : orig0;
                    bool ok   = s ? r1 : r0;
                    bkey[r] = key;
                    if (ok) {
                        float4 bb = wb[orig];
                        float off = fmul((float)cls_id_b[orig], M);  // c.astype(f32)*(max+1)
                        float x1 = fadd(bb.x, off), y1 = fadd(bb.y, off);
                        float x2 = fadd(bb.z, off), y2 = fadd(bb.w, off);
                        bbox[r] = make_float4(x1, y1, x2, y2);
                        barr[r] = fmul(fmaxf(fsub(x2, x1), 0.f), fmaxf(fsub(y2, y1), 0.f));
                        borig[r] = orig;
                    } else {
                        bbox[r] = make_float4(0.f, 0.f, 0.f, 0.f);
                        barr[r] = 0.f;
                        borig[r] = -1;
                    }
                }
            }
            // pointer advance: count consumed (real) winners and A-side winners
            u64 bR0 = __ballot(r0), bR1 = __ballot(r1);
            u64 bA0 = __ballot(r0 && (orig0 < HALF));
            u64 bA1 = __ballot(r1 && (orig1 < HALF));
            int real = __popcll(bR0) + __popcll(bR1);
            int aw   = __popcll(bA0) + __popcll(bA1);
            pa += aw;
            pb += real - aw;
        }
        __syncthreads();

        // ---- 2. all 16 waves: suppression partials (validated R7 structure) ----
        float4 c4  = bbox[j];
        float  car = barr[j];
        const bool valid = (borig[j] >= 0);

        bool sup = !valid;
        for (int k = g; k < count; k += 16) {
            float4 h4 = hbox4[k];
            sup = sup | iou_suppress(h4.x, h4.y, h4.z, h4.w, harr[k],
                                     c4.x, c4.y, c4.z, c4.w, car);
        }
        u64 bal = __ballot(sup ? 1 : 0);
        if ((t & 63) == 0) extp[g] = bal;

        unsigned cplo = 0, cphi = 0;
        for (int r = g + 1; r < 64; r += 16) {
            int q = j ^ r;
            float4 q4 = bbox[q];
            float qar = barr[q];
            bool hit = (q > j) & valid & (borig[q] >= 0) &
                       iou_suppress(c4.x, c4.y, c4.z, c4.w, car,
                                    q4.x, q4.y, q4.z, q4.w, qar);
            unsigned bit = hit ? 1u : 0u;
            if (q < 32) cplo |= bit << q; else cphi |= bit << (q - 32);
        }
        Cplo[g][j] = cplo;
        Cphi[g][j] = cphi;
        __syncthreads();

        // ---- 3. wave 0: combine partials, exact greedy closure, append heads ----
        if (t < 64) {
            const int lane = t;
            u64 ext = 0;
            #pragma unroll
            for (int gg = 0; gg < 16; ++gg) ext |= extp[gg];
            unsigned lo = 0, hi = 0;
            #pragma unroll
            for (int gg = 0; gg < 16; ++gg) { lo |= Cplo[gg][lane]; hi |= Cphi[gg][lane]; }
            u64 C = ((u64)hi << 32) | lo;
            u64 hasC = __ballot(C != 0ull);

            u64 alive = ~ext;
            u64 selmask = 0;
            int total = count;
            while (alive && total < MAX_DET) {
                int k = __ffsll(alive) - 1;
                selmask |= (1ull << k);
                alive &= ~(1ull << k);
                ++total;
                if ((hasC >> k) & 1ull) {
                    unsigned clo = __shfl((int)(unsigned)C, k, 64);
                    unsigned chi = __shfl((int)(unsigned)(C >> 32), k, 64);
                    alive &= ~(((u64)chi << 32) | clo);
                }
            }

            if ((selmask >> lane) & 1ull) {
                int p = count + __popcll(selmask & ((1ull << lane) - 1ull));
                hbox4[p] = bbox[lane];
                harr[p]  = barr[lane];
                sel[p]   = borig[lane];
                selsc[p] = __uint_as_float((unsigned)(bkey[lane] >> 32));  // exact sigmoid bits
            }
            if (lane == 0) sh_count = total;
        }
        __syncthreads();
    }

    // ---------- Emit (wave 0; validated path) ----------
    if (t >= 64) return;
    for (int r = t; r < MAX_DET; r += 64) {
        int sidx = sel[r];
        float* o = out + (size_t)b * MAX_DET * 6 + (size_t)r * 6;
        if (sidx < 0) {
            o[0] = 0.f; o[1] = 0.f; o[2] = 0.f; o[3] = 0.f; o[4] = 0.f; o[5] = 0.f;
        } else {
            float4 bb = wb[sidx];
            int c = cls_id_b[sidx];
            o[0] = fmul(bb.x, scale);
            o[1] = fmul(bb.y, scale);
            o[2] = fmul(bb.z, scale);
            o[3] = fmul(bb.w, scale);
            o[4] = selsc[r];
            o[5] = (float)(c + 1);
        }
    }
}

extern "C" void kernel_launch(void* const* d_in, const int* in_sizes, int n_in,
                              void* d_out, int out_size, void* d_ws, size_t ws_size,
                              hipStream_t stream)
{
    const float* cls_outputs = (const float*)d_in[0];
    const float* box_outputs = (const float*)d_in[1];
    const int*   indices     = (const int*)d_in[2];
    const int*   classes     = (const int*)d_in[3];
    const float* anchors     = (const float*)d_in[4];
    const float* img_scale   = (const float*)d_in[5];
    const float* img_size    = (const float*)d_in[6];
    float*       out         = (float*)d_out;

    const int B = in_sizes[5];   // img_scale has B elements

    // workspace layout: [wmax: B*8 floats][pad to 1KB][wkeys: B*4096 u64][wboxes: B*4096 float4]
    char* wsb = (char*)d_ws;
    float*  wmax   = (float*)wsb;
    u64*    wkeys  = (u64*)(wsb + 1024);
    float4* wboxes = (float4*)(wsb + 1024 + (size_t)B * N_DET * sizeof(u64));

    decode_kernel<<<dim3(B * DEC_CHUNKS), dim3(DEC_THREADS), 0, stream>>>(
        cls_outputs, box_outputs, indices, anchors, img_scale, img_size,
        wmax, wkeys, wboxes);

    sort_half_kernel<<<dim3(B * 2), dim3(SORT_THREADS), 0, stream>>>(wkeys);

    scan_kernel<<<dim3(B), dim3(NTHREADS), 0, stream>>>(
        classes, img_scale, wmax, wkeys, wboxes, out);
}

// Round 9
// 40.119 us; speedup vs baseline: 1.7467x; 1.0323x over previous
//
#include <hip/hip_runtime.h>
#include <stdint.h>

#define N_DET    4096
#define HALF     2048
#define MAX_DET  100
#define NTHREADS 1024
#define SORT_THREADS 512
#define DEC_THREADS 256
#define DEC_CHUNKS  16       // blocks per batch in decode kernel
#define IOU_THR  0.5f

typedef unsigned long long u64;

// Explicit-rounding helpers: prevent -ffp-contract=fast from FMA-fusing and
// changing bits vs the JAX/NumPy reference (R1-R8 all passed with absmax 0.0).
__device__ __forceinline__ float fadd(float a, float b) { return __fadd_rn(a, b); }
__device__ __forceinline__ float fsub(float a, float b) { return __fsub_rn(a, b); }
__device__ __forceinline__ float fmul(float a, float b) { return __fmul_rn(a, b); }

struct Box { float x1, y1, x2, y2; };

__device__ __forceinline__ Box decode_box(const float* __restrict__ box_b,
                                          const int*   __restrict__ idx_b,
                                          const float* __restrict__ anchors,
                                          int i, float sz0, float sz1)
{
    int ai = idx_b[i];
    float a0 = anchors[ai * 4 + 0];
    float a1 = anchors[ai * 4 + 1];
    float a2 = anchors[ai * 4 + 2];
    float a3 = anchors[ai * 4 + 3];
    float yc_a = fmul(fadd(a0, a2), 0.5f);
    float xc_a = fmul(fadd(a1, a3), 0.5f);
    float ha = fsub(a2, a0);
    float wa = fsub(a3, a1);
    float ty = box_b[i * 4 + 0];
    float tx = box_b[i * 4 + 1];
    float th = box_b[i * 4 + 2];
    float tw = box_b[i * 4 + 3];
    float we = fmul(expf(tw), wa);
    float he = fmul(expf(th), ha);
    float yc = fadd(fmul(ty, ha), yc_a);
    float xc = fadd(fmul(tx, wa), xc_a);
    Box r;
    r.x1 = fsub(xc, fmul(we, 0.5f));
    r.y1 = fsub(yc, fmul(he, 0.5f));
    r.x2 = fadd(xc, fmul(we, 0.5f));
    r.y2 = fadd(yc, fmul(he, 0.5f));
    r.x1 = fminf(fmaxf(r.x1, 0.f), sz0);
    r.y1 = fminf(fmaxf(r.y1, 0.f), sz1);
    r.x2 = fminf(fmaxf(r.x2, 0.f), sz0);
    r.y2 = fminf(fmaxf(r.y2, 0.f), sz1);
    return r;
}

__device__ __forceinline__ float sigmoidf_ref(float x)
{
    return __fdiv_rn(1.0f, __fadd_rn(1.0f, expf(-x)));
}

// head (earlier-selected) first: union = area[head] + area[cand] - inter
__device__ __forceinline__ bool iou_suppress(float hx1, float hy1, float hx2, float hy2, float har,
                                             float cx1, float cy1, float cx2, float cy2, float car)
{
    float lt0 = fmaxf(hx1, cx1);
    float lt1 = fmaxf(hy1, cy1);
    float rb0 = fminf(hx2, cx2);
    float rb1 = fminf(hy2, cy2);
    float w0 = fmaxf(fsub(rb0, lt0), 0.f);
    float w1 = fmaxf(fsub(rb1, lt1), 0.f);
    float inter = fmul(w0, w1);
    float uni = fsub(fadd(har, car), inter);
    float iou = __fdiv_rn(inter, fmaxf(uni, 1e-8f));
    return iou > IOU_THR;
}

// ---- bitonic helpers (register / shuffle) ----
__device__ __forceinline__ u64 shfl_xor_u64(u64 x, int mask)
{
    unsigned lo = (unsigned)x, hi = (unsigned)(x >> 32);
    lo = __shfl_xor(lo, mask, 64);
    hi = __shfl_xor(hi, mask, 64);
    return ((u64)hi << 32) | lo;
}

__device__ __forceinline__ void cex(u64& a, u64& b, bool desc)
{
    bool sw = desc ? (a < b) : (a > b);
    u64 ta = a, tb = b;
    a = sw ? tb : ta;
    b = sw ? ta : tb;
}

__device__ __forceinline__ void shuf_pass(u64 e[4], int d, bool desc, int l)
{
    bool lower = ((l & d) == 0);
    bool keepmax = (desc == lower);
    #pragma unroll
    for (int s = 0; s < 4; ++s) {
        u64 p = shfl_xor_u64(e[s], d);
        u64 mx = (e[s] > p) ? e[s] : p;
        u64 mn = (e[s] < p) ? e[s] : p;
        e[s] = keepmax ? mx : mn;
    }
}

// 2-slot descending merge step: element idx = 2*lane + slot, partner lane = l ^ d.
__device__ __forceinline__ void shuf_pass2(u64 e[2], int d, int l)
{
    bool keepmax = ((l & d) == 0);
    #pragma unroll
    for (int s = 0; s < 2; ++s) {
        u64 p = shfl_xor_u64(e[s], d);
        u64 mx = (e[s] > p) ? e[s] : p;
        u64 mn = (e[s] < p) ? e[s] : p;
        e[s] = keepmax ? mx : mn;
    }
}

// =====================  Kernel 1: wide-grid decode (validated R6-R8; wider grid)  =====================
__global__ __launch_bounds__(DEC_THREADS)
void decode_kernel(const float* __restrict__ cls_outputs,
                   const float* __restrict__ box_outputs,
                   const int*   __restrict__ indices,
                   const float* __restrict__ anchors,
                   const float* __restrict__ img_scale,
                   const float* __restrict__ img_size,
                   float*       __restrict__ wmax,    // B * DEC_CHUNKS
                   u64*         __restrict__ wkeys,   // B * N_DET
                   float4*      __restrict__ wboxes)  // B * N_DET
{
    const int blk   = blockIdx.x;
    const int b     = blk / DEC_CHUNKS;
    const int chunk = blk % DEC_CHUNKS;
    const int i     = chunk * DEC_THREADS + threadIdx.x;

    const float* cls_b = cls_outputs + (size_t)b * N_DET;
    const float* box_b = box_outputs + (size_t)b * N_DET * 4;
    const int*   idx_b = indices + (size_t)b * N_DET;
    const float  scale = img_scale[b];
    const float  sz0   = __fdiv_rn(img_size[b * 2 + 0], scale);
    const float  sz1   = __fdiv_rn(img_size[b * 2 + 1], scale);

    Box r = decode_box(box_b, idx_b, anchors, i, sz0, sz1);
    float sc = sigmoidf_ref(cls_b[i]);

    wboxes[(size_t)b * N_DET + i] = make_float4(r.x1, r.y1, r.x2, r.y2);
    wkeys[(size_t)b * N_DET + i] =
        ((u64)__float_as_uint(sc) << 32) | (unsigned)(N_DET - 1 - i);

    float lmax = fmaxf(fmaxf(r.x1, r.y1), fmaxf(r.x2, r.y2));
    for (int o = 32; o; o >>= 1) lmax = fmaxf(lmax, __shfl_xor(lmax, o, 64));
    __shared__ float wred[DEC_THREADS / 64];
    if ((threadIdx.x & 63) == 0) wred[threadIdx.x >> 6] = lmax;
    __syncthreads();
    if (threadIdx.x == 0) {
        float m = wred[0];
        #pragma unroll
        for (int k = 1; k < DEC_THREADS / 64; ++k) m = fmaxf(m, wred[k]);
        wmax[b * DEC_CHUNKS + chunk] = m;   // plain store: overwritten every replay
    }
}

// =====================  Kernel 2: sort one 2048-half in place (validated R8)  =====================
__global__ __launch_bounds__(SORT_THREADS, 1)
void sort_half_kernel(u64* __restrict__ wkeys)
{
    __shared__ u64 keys[HALF];     // 16 KB
    u64* gk = wkeys + (size_t)blockIdx.x * HALF;
    const int t = threadIdx.x;
    const int l = t & 63;

    u64 e[4];
    #pragma unroll
    for (int s = 0; s < 4; ++s) e[s] = gk[4 * t + s];

    // Phase A (validated): wave-local bitonic, k=2..256; i = 4t+s, desc <=> (i&k)==0
    cex(e[0], e[1], true);
    cex(e[2], e[3], false);
    for (int k = 4; k <= 128; k <<= 1) {
        bool desc = (l & (k >> 2)) == 0;
        for (int j = k >> 1; j >= 4; j >>= 1) shuf_pass(e, j >> 2, desc, l);
        cex(e[0], e[2], desc); cex(e[1], e[3], desc);
        cex(e[0], e[1], desc); cex(e[2], e[3], desc);
    }
    {   // k = 256: wave-parity direction
        bool desc = ((t >> 6) & 1) == 0;
        for (int j = 128; j >= 4; j >>= 1) shuf_pass(e, j >> 2, desc, l);
        cex(e[0], e[2], desc); cex(e[1], e[3], desc);
        cex(e[0], e[1], desc); cex(e[2], e[3], desc);
    }
    #pragma unroll
    for (int s = 0; s < 4; ++s) keys[4 * t + s] = e[s];

    // Phase B (validated): cross-wave merges k = 512..2048
    for (int k = 512; k <= HALF; k <<= 1) {
        for (int j = k >> 1; j >= 256; j >>= 1) {
            __syncthreads();
            #pragma unroll
            for (int vv = 0; vv < 2; ++vv) {
                int v = t + vv * SORT_THREADS;          // 0..1023 pairs
                int i   = ((v & ~(j - 1)) << 1) | (v & (j - 1));
                int ixj = i | j;
                bool desc = ((i & k) == 0);
                u64 a = keys[i], c = keys[ixj];
                bool sw = desc ? (a < c) : (a > c);
                if (sw) { keys[i] = c; keys[ixj] = a; }
            }
        }
        __syncthreads();
        u64 f[4];
        #pragma unroll
        for (int s = 0; s < 4; ++s) f[s] = keys[4 * t + s];
        bool desc = (t & (k >> 2)) == 0;               // (4t&k)==0
        for (int j = 128; j >= 4; j >>= 1) shuf_pass(f, j >> 2, desc, l);
        cex(f[0], f[2], desc); cex(f[1], f[3], desc);
        cex(f[0], f[1], desc); cex(f[2], f[3], desc);
        #pragma unroll
        for (int s = 0; s < 4; ++s) keys[4 * t + s] = f[s];
    }
    __syncthreads();
    #pragma unroll
    for (int s = 0; s < 4; ++s) gk[4 * t + s] = keys[4 * t + s];
}

// =====================  Kernel 3: pre-merged top-512 stream + block-parallel scan  =====================
__global__ __launch_bounds__(NTHREADS, 1)
void scan_kernel(const int*    __restrict__ classes,    // B,N
                 const float*  __restrict__ img_scale,  // B
                 const float*  __restrict__ wmax,
                 const u64*    __restrict__ wkeys,      // sorted halves
                 const float4* __restrict__ wboxes,
                 float*        __restrict__ out)        // B,MAX_DET,6
{
    __shared__ u64    mstream[1024];   // merged A[0:512] ∪ B[0:512]; [0:512] = exact global top-512
    __shared__ int    waveA[8];
    __shared__ float4 bbox[64];
    __shared__ float  barr[64];
    __shared__ int    borig[64];
    __shared__ u64    bkey[64];
    __shared__ u64    extp[16];
    __shared__ unsigned Cplo[16][64];
    __shared__ unsigned Cphi[16][64];
    __shared__ int    sel[MAX_DET];
    __shared__ float  selsc[MAX_DET];
    __shared__ float4 hbox4[MAX_DET];
    __shared__ float  harr[MAX_DET];
    __shared__ int    sh_count;

    const int b = blockIdx.x;
    const int t = threadIdx.x;
    const int l = t & 63;

    const int*    cls_id_b = classes + (size_t)b * N_DET;
    const float   scale    = img_scale[b];
    const u64*    gA = wkeys + (size_t)b * N_DET;    // half A: orig 0..2047, desc
    const u64*    gB = gA + HALF;                    // half B: orig 2048..4095, desc
    const float4* wb = wboxes + (size_t)b * N_DET;

    float mm = wmax[b * DEC_CHUNKS + 0];
    #pragma unroll
    for (int k = 1; k < DEC_CHUNKS; ++k) mm = fmaxf(mm, wmax[b * DEC_CHUNKS + k]);
    const float M = fadd(mm, 1.0f);   // jnp.max(b) + 1.0

    // ---------- Pre-merge: mstream = A[0:512] desc ++ B[0:512] asc (bitonic) ----------
    if (t < 512) mstream[t] = gA[t];
    else         mstream[t] = gB[511 - (t - 512)];
    if (t < MAX_DET) sel[t] = -1;
    if (t == 0) sh_count = 0;
    __syncthreads();

    // Descending merge network, j = 512, 256 (LDS), then j<=128 (blocked registers).
    {   // j = 512
        if (t < 512) {
            u64 a = mstream[t], c = mstream[t + 512];
            if (a < c) { mstream[t] = c; mstream[t + 512] = a; }
        }
        __syncthreads();
        // j = 256
        if (t < 512) {
            int i   = ((t & ~255) << 1) | (t & 255);
            int ixj = i | 256;
            u64 a = mstream[i], c = mstream[ixj];
            if (a < c) { mstream[i] = c; mstream[ixj] = a; }
        }
        __syncthreads();
        // j = 128..1 : blocked register phase (validated formulas, desc = true)
        if (t < 256) {
            u64 f[4];
            #pragma unroll
            for (int s = 0; s < 4; ++s) f[s] = mstream[4 * t + s];
            for (int j = 128; j >= 4; j >>= 1) shuf_pass(f, j >> 2, true, l);
            cex(f[0], f[2], true); cex(f[1], f[3], true);
            cex(f[0], f[1], true); cex(f[2], f[3], true);
            #pragma unroll
            for (int s = 0; s < 4; ++s) mstream[4 * t + s] = f[s];
        }
        __syncthreads();
    }

    // count A-side elements in the top-512 (exact resume pointers for fallback)
    {
        bool isA = false;
        if (t < 512) {
            int orig = N_DET - 1 - (int)(unsigned)(mstream[t] & 0xFFFFFFFFull);
            isA = (orig < HALF);
        }
        u64 bal = __ballot(isA ? 1 : 0);
        if ((t & 63) == 0 && (t >> 6) < 8) waveA[t >> 6] = __popcll(bal);
        __syncthreads();
    }
    int pa = 0;
    #pragma unroll
    for (int w = 0; w < 8; ++w) pa += waveA[w];
    int pb = 512 - pa;                 // fallback resume pointers (uniform)

    const int j = t & 63;
    const int g = t >> 6;

    for (int c = 0; c < N_DET; c += 64) {
        int count = sh_count;          // uniform after barrier
        if (count >= MAX_DET) break;

        if (c + 64 <= 512) {
            // ---- 1-fast. publish from pre-merged stream (parallel, no serial merge) ----
            if (t < 64) {
                u64 key = mstream[c + t];
                int orig = N_DET - 1 - (int)(unsigned)(key & 0xFFFFFFFFull);
                bkey[t] = key; borig[t] = orig;
                float4 bb = wb[orig];
                float off = fmul((float)cls_id_b[orig], M);  // c.astype(f32)*(max+1)
                float x1 = fadd(bb.x, off), y1 = fadd(bb.y, off);
                float x2 = fadd(bb.z, off), y2 = fadd(bb.w, off);
                bbox[t] = make_float4(x1, y1, x2, y2);
                barr[t] = fmul(fmaxf(fsub(x2, x1), 0.f), fmaxf(fsub(y2, y1), 0.f));
            }
        } else {
            // ---- 1-slow. fallback: windowed 2-way merge (validated R8; exact, rare) ----
            if (t < 64) {
                u64 ee[2];
                if (l < 32) {
                    int p0 = pa + 2 * l;
                    ee[0] = (p0     < HALF) ? gA[p0]     : 0ull;
                    ee[1] = (p0 + 1 < HALF) ? gA[p0 + 1] : 0ull;
                } else {
                    int p  = 2 * (l - 32);
                    int q0 = pb + 63 - p;
                    ee[0] = (q0     < HALF) ? gB[q0]     : 0ull;
                    ee[1] = (q0 - 1 < HALF && q0 - 1 >= 0) ? gB[q0 - 1] : 0ull;
                }
                shuf_pass2(ee, 32, l); shuf_pass2(ee, 16, l); shuf_pass2(ee, 8, l);
                shuf_pass2(ee, 4, l);  shuf_pass2(ee, 2, l);  shuf_pass2(ee, 1, l);
                cex(ee[0], ee[1], true);

                int orig0 = N_DET - 1 - (int)(unsigned)(ee[0] & 0xFFFFFFFFull);
                int orig1 = N_DET - 1 - (int)(unsigned)(ee[1] & 0xFFFFFFFFull);
                bool r0 = (l < 32) && (ee[0] != 0ull);
                bool r1 = (l < 32) && (ee[1] != 0ull);
                if (l < 32) {
                    #pragma unroll
                    for (int s = 0; s < 2; ++s) {
                        int  r    = 2 * l + s;
                        u64  key  = s ? ee[1] : ee[0];
                        int  orig = s ? orig1 : orig0;
                        bool ok   = s ? r1 : r0;
                        bkey[r] = key;
                        if (ok) {
                            float4 bb = wb[orig];
                            float off = fmul((float)cls_id_b[orig], M);
                            float x1 = fadd(bb.x, off), y1 = fadd(bb.y, off);
                            float x2 = fadd(bb.z, off), y2 = fadd(bb.w, off);
                            bbox[r] = make_float4(x1, y1, x2, y2);
                            barr[r] = fmul(fmaxf(fsub(x2, x1), 0.f), fmaxf(fsub(y2, y1), 0.f));
                            borig[r] = orig;
                        } else {
                            bbox[r] = make_float4(0.f, 0.f, 0.f, 0.f);
                            barr[r] = 0.f;
                            borig[r] = -1;
                        }
                    }
                }
                u64 bR0 = __ballot(r0), bR1 = __ballot(r1);
                u64 bA0 = __ballot(r0 && (orig0 < HALF));
                u64 bA1 = __ballot(r1 && (orig1 < HALF));
                int real = __popcll(bR0) + __popcll(bR1);
                int aw   = __popcll(bA0) + __popcll(bA1);
                pa += aw;
                pb += real - aw;
            }
        }
        __syncthreads();

        // ---- 2. all 16 waves: suppression partials (validated R7/R8) ----
        float4 c4  = bbox[j];
        float  car = barr[j];
        const bool valid = (borig[j] >= 0);

        bool sup = !valid;
        for (int k = g; k < count; k += 16) {
            float4 h4 = hbox4[k];
            sup = sup | iou_suppress(h4.x, h4.y, h4.z, h4.w, harr[k],
                                     c4.x, c4.y, c4.z, c4.w, car);
        }
        u64 bal = __ballot(sup ? 1 : 0);
        if ((t & 63) == 0) extp[g] = bal;

        unsigned cplo = 0, cphi = 0;
        for (int r = g + 1; r < 64; r += 16) {
            int q = j ^ r;
            float4 q4 = bbox[q];
            float qar = barr[q];
            bool hit = (q > j) & valid & (borig[q] >= 0) &
                       iou_suppress(c4.x, c4.y, c4.z, c4.w, car,
                                    q4.x, q4.y, q4.z, q4.w, qar);
            unsigned bit = hit ? 1u : 0u;
            if (q < 32) cplo |= bit << q; else cphi |= bit << (q - 32);
        }
        Cplo[g][j] = cplo;
        Cphi[g][j] = cphi;
        __syncthreads();

        // ---- 3. wave 0: combine partials, exact greedy closure, append heads ----
        if (t < 64) {
            const int lane = t;
            u64 ext = 0;
            #pragma unroll
            for (int gg = 0; gg < 16; ++gg) ext |= extp[gg];
            unsigned lo = 0, hi = 0;
            #pragma unroll
            for (int gg = 0; gg < 16; ++gg) { lo |= Cplo[gg][lane]; hi |= Cphi[gg][lane]; }
            u64 C = ((u64)hi << 32) | lo;
            u64 hasC = __ballot(C != 0ull);

            u64 alive = ~ext;
            u64 selmask = 0;
            int total = count;
            while (alive && total < MAX_DET) {
                int k = __ffsll(alive) - 1;
                selmask |= (1ull << k);
                alive &= ~(1ull << k);
                ++total;
                if ((hasC >> k) & 1ull) {
                    unsigned clo = __shfl((int)(unsigned)C, k, 64);
                    unsigned chi = __shfl((int)(unsigned)(C >> 32), k, 64);
                    alive &= ~(((u64)chi << 32) | clo);
                }
            }

            if ((selmask >> lane) & 1ull) {
                int p = count + __popcll(selmask & ((1ull << lane) - 1ull));
                hbox4[p] = bbox[lane];
                harr[p]  = barr[lane];
                sel[p]   = borig[lane];
                selsc[p] = __uint_as_float((unsigned)(bkey[lane] >> 32));  // exact sigmoid bits
            }
            if (lane == 0) sh_count = total;
        }
        __syncthreads();
    }

    // ---------- Emit (wave 0; validated path) ----------
    if (t >= 64) return;
    for (int r = t; r < MAX_DET; r += 64) {
        int sidx = sel[r];
        float* o = out + (size_t)b * MAX_DET * 6 + (size_t)r * 6;
        if (sidx < 0) {
            o[0] = 0.f; o[1] = 0.f; o[2] = 0.f; o[3] = 0.f; o[4] = 0.f; o[5] = 0.f;
        } else {
            float4 bb = wb[sidx];
            int c = cls_id_b[sidx];
            o[0] = fmul(bb.x, scale);
            o[1] = fmul(bb.y, scale);
            o[2] = fmul(bb.z, scale);
            o[3] = fmul(bb.w, scale);
            o[4] = selsc[r];
            o[5] = (float)(c + 1);
        }
    }
}

extern "C" void kernel_launch(void* const* d_in, const int* in_sizes, int n_in,
                              void* d_out, int out_size, void* d_ws, size_t ws_size,
                              hipStream_t stream)
{
    const float* cls_outputs = (const float*)d_in[0];
    const float* box_outputs = (const float*)d_in[1];
    const int*   indices     = (const int*)d_in[2];
    const int*   classes     = (const int*)d_in[3];
    const float* anchors     = (const float*)d_in[4];
    const float* img_scale   = (const float*)d_in[5];
    const float* img_size    = (const float*)d_in[6];
    float*       out         = (float*)d_out;

    const int B = in_sizes[5];   // img_scale has B elements

    // workspace layout: [wmax: B*16 floats][pad to 1KB][wkeys: B*4096 u64][wboxes: B*4096 float4]
    char* wsb = (char*)d_ws;
    float*  wmax   = (float*)wsb;
    u64*    wkeys  = (u64*)(wsb + 1024);
    float4* wboxes = (float4*)(wsb + 1024 + (size_t)B * N_DET * sizeof(u64));

    decode_kernel<<<dim3(B * DEC_CHUNKS), dim3(DEC_THREADS), 0, stream>>>(
        cls_outputs, box_outputs, indices, anchors, img_scale, img_size,
        wmax, wkeys, wboxes);

    sort_half_kernel<<<dim3(B * 2), dim3(SORT_THREADS), 0, stream>>>(wkeys);

    scan_kernel<<<dim3(B), dim3(NTHREADS), 0, stream>>>(
        classes, img_scale, wmax, wkeys, wboxes, out);
}